// Round 6
// baseline (18.446 us; speedup 1.0000x reference)
//
#include <hip/hip_runtime.h>

// RayTracing: B=4, P=32768 rays, analytic sphere SDF.
// R3 skeleton (2 lanes/ray, no barriers, no atomics) with the serial tail
// shortened: the 100-step march scan is replaced by f64 analytic root
// windows (+ bit-identical predicate verification), and the 8-iter secant
// by the analytic root of u(z)=rad^2.

#define SDF_THR   5e-05f
#define NSTEPS    100
#define NTRACE    10

__device__ __forceinline__ float fsqrt(float x) {
    float r; asm("v_sqrt_f32 %0, %1" : "=v"(r) : "v"(x)); return r;
}
__device__ __forceinline__ float frcp(float x) {
    float r; asm("v_rcp_f32 %0, %1" : "=v"(r) : "v"(x)); return r;
}

__global__ __launch_bounds__(256) void ray_kernel(
    const float* __restrict__ cam_loc,     // [B,3]
    const float* __restrict__ ray_dirs,    // [B,P,3]
    const float* __restrict__ sdf_center,  // [3]
    const float* __restrict__ sdf_radius,  // [1]
    float* __restrict__ out,               // [3N pts | N mask | N dist]
    int n_total)
{
    const int t = blockIdx.x * blockDim.x + threadIdx.x;
    const int n = t >> 1;                  // ray index
    const int h = t & 1;                   // 0 = start end, 1 = far end
    if (n >= n_total) return;
    const int b = n >> 15;                 // n / P, P = 32768

    const float dx = ray_dirs[3*n+0], dy = ray_dirs[3*n+1], dz = ray_dirs[3*n+2];
    const float cx = cam_loc[3*b+0], cy = cam_loc[3*b+1], cz = cam_loc[3*b+2];
    const float scx = sdf_center[0], scy = sdf_center[1], scz = sdf_center[2];
    const float rad = sdf_radius[0];

    // quadratic coeffs of squared distance along ray (+1e-12 folded in)
    const float ex = cx - scx, ey = cy - scy, ez = cz - scz;
    const float dd  = dx*dx + dy*dy + dz*dz;
    const float de2 = 2.0f * (dx*ex + dy*ey + dz*ez);
    const float ee1 = (ex*ex + ey*ey + ez*ez) + 1e-12f;

    // ---- bounding-sphere intersection (R=1) ----
    float rcd  = dx*cx + dy*cy + dz*cz;
    float cam2 = cx*cx + cy*cy + cz*cz;
    float under = rcd*rcd - (cam2 - 1.0f);
    bool mask_int = under > 0.0f;
    float sq = fsqrt(mask_int ? under : 0.0f);
    float si0 = fmaxf(mask_int ? (-sq - rcd) : 0.0f, 0.0f);
    float si1 = fmaxf(mask_int ? ( sq - rcd) : 0.0f, 0.0f);

    // ---- sphere tracing: this lane owns one end ----
    float my_acc = h ? si1 : si0;
    const float sgn = h ? -1.0f : 1.0f;     // s end adds, e end subtracts
    bool my_unfin = mask_int;
    float next;
    {
        float u0 = fmaf(my_acc, fmaf(my_acc, dd, de2), ee1);
        next = my_unfin ? (fsqrt(u0) - rad) : 0.0f;
    }

    float acc_s = my_acc, acc_e = my_acc;
    #pragma unroll
    for (int it = 0; it < NTRACE; ++it) {
        float curr = my_unfin ? next : 0.0f;
        curr = (curr <= SDF_THR) ? 0.0f : curr;
        my_unfin = my_unfin && (curr > SDF_THR);
        my_acc = fmaf(sgn, curr, my_acc);
        float u = fmaf(my_acc, fmaf(my_acc, dd, de2), ee1);
        next = my_unfin ? (fsqrt(u) - rad) : 0.0f;
        // line-search back-off: exact SDF -> essentially never taken
        if (next < 0.0f) {
            my_acc = fmaf(-sgn, 0.5f * curr, my_acc);
            float u2 = fmaf(my_acc, fmaf(my_acc, dd, de2), ee1);
            next = fsqrt(u2) - rad;
        }
        float pacc = __shfl_xor(my_acc, 1);
        acc_s = h ? pacc : my_acc;
        acc_e = h ? my_acc : pacc;
        bool ok = acc_s < acc_e;
        my_unfin = my_unfin && ok;
    }
    // final mask refresh (only the s-lane's value matters for the ray)
    bool sampler_s = my_unfin;
    {
        float curr = my_unfin ? next : 0.0f;
        curr = (curr <= SDF_THR) ? 0.0f : curr;
        sampler_s = my_unfin && (curr > SDF_THR);
    }
    const bool netmask_trace = acc_s < acc_e;

    // ray-level sampler flag on both lanes
    int smi = __shfl_xor(h ? 0 : (int)sampler_s, 1);
    const bool sampler = h ? (smi != 0) : sampler_s;

    // ---- sampler path: analytic march windows + analytic "secant" ----
    bool net_surface = false;
    float z_pred = 0.0f, zh_out = 0.0f;
    float pix = 0.0f, piy = 0.0f, piz = 0.0f;

    if (__ballot(sampler) != 0ULL) {
        const float smin = sampler ? acc_s : 0.0f;
        const float smax = sampler ? acc_e : 0.0f;
        const float sz = (smax - smin) * (1.0f / 99.0f);   // z_i = fma(i,sz,smin)

        // v_sqrt-consistent thresholds: fsqrt(u) < rad  <=> u <= u_neg_max
        //                                fsqrt(u) <= rad <=> u <= u_le_max
        float r2 = rad * rad;
        unsigned rb = __float_as_uint(r2);
        float u_neg_max = __uint_as_float(rb - 7u);
        float u_le_max  = u_neg_max;
        #pragma unroll
        for (int k = -6; k <= 6; ++k) {
            float u = __uint_as_float(rb + (unsigned)k);
            float v = fsqrt(u);
            if (v <  rad) u_neg_max = u;   // ascending: last wins = max
            if (v <= rad) u_le_max  = u;
        }

        // f64 roots of u(z) = u_le_max  (f64 needed: tangency cancellation and
        // tiny-sz sampler rays make f32 index estimates off by >2 steps)
        const double dBh = 0.5 * (double)de2;
        const double ddd = (double)dd;
        const double dCc = (double)ee1 - (double)u_le_max;
        double ddisc = dBh * dBh - ddd * dCc;
        double dsq = sqrt(ddisc > 0.0 ? ddisc : 0.0);
        float zm = (float)((-dBh - dsq) / ddd);   // entry root
        float zv = (float)(-dBh / ddd);           // vertex (min of u)

        const float inv_sz = frcp(sz);
        float fie = floorf((zm - smin) * inv_sz);
        float fiv = floorf((zv - smin) * inv_sz);
        int ie = (int)fminf(fmaxf(fie, 0.0f), 99.0f);
        int iv = (int)fminf(fmaxf(fiv, 0.0f), 99.0f);

        // first index with u_i <= u_le_max lies in these windows (predicate
        // bit-identical to the trace's u-form, so 0/99 can't be members and
        // the contiguous membership set starts near the analytic entry)
        int kfound = 1000;
        #pragma unroll
        for (int w = -3; w <= 3; ++w) {
            int i = ie + w;
            float fi = (float)i;
            float z = fmaf(fi, sz, smin);
            float u = fmaf(z, fmaf(z, dd, de2), ee1);
            bool hit = (i >= 0) && (i < NSTEPS) && (u <= u_le_max);
            if (hit && i < kfound) kfound = i;
        }
        #pragma unroll
        for (int w = -3; w <= 3; ++w) {
            int i = iv + w;
            float fi = (float)i;
            float z = fmaf(fi, sz, smin);
            float u = fmaf(z, fmaf(z, dd, de2), ee1);
            bool hit = (i >= 0) && (i < NSTEPS) && (u <= u_le_max);
            if (hit && i < kfound) kfound = i;
        }

        int ind;
        if (kfound < NSTEPS) {
            int km = kfound;
            float zk = fmaf((float)km, sz, smin);
            float uk = fmaf(zk, fmaf(zk, dd, de2), ee1);
            if (uk <= u_neg_max) {
                ind = km; net_surface = true;     // first crossing is negative
            } else {
                // exact-tie (sdf==0) at km: reference prefers first NEGATIVE
                // anywhere after; near-never taken -> plain loop, execz-skipped
                ind = km; net_surface = false;
                for (int i = km + 1; i < NSTEPS; ++i) {
                    float z = fmaf((float)i, sz, smin);
                    float u = fmaf(z, fmaf(z, dd, de2), ee1);
                    if (u <= u_neg_max) { ind = i; net_surface = true; break; }
                }
            }
        } else {
            ind = NSTEPS - 1; net_surface = false;
        }

        zh_out = fmaf((float)ind, sz, smin);      // reference outputs z[ind]
        pix = fmaf(zh_out, dx, cx);
        piy = fmaf(zh_out, dy, cy);
        piz = fmaf(zh_out, dz, cz);

        // analytic replacement of the 8-iter secant: root of u(z) = rad^2
        // inside [z_low, z_high] = the entry root (only used when net_surface)
        float Bh = 0.5f * de2;
        float disc2 = fmaf(-dd, ee1 - r2, Bh * Bh);
        z_pred = (-Bh - fsqrt(fmaxf(disc2, 0.0f))) * frcp(dd);
    }

    // ---- final selection ----
    float ox, oy, oz, odis;
    bool omask;
    if (sampler) {
        if (net_surface) {
            ox = fmaf(z_pred, dx, cx);
            oy = fmaf(z_pred, dy, cy);
            oz = fmaf(z_pred, dz, cz);
            odis = z_pred;
        } else {
            ox = pix; oy = piy; oz = piz;
            odis = zh_out;
        }
        omask = net_surface;
    } else {
        ox = fmaf(acc_s, dx, cx);
        oy = fmaf(acc_s, dy, cy);
        oz = fmaf(acc_s, dz, cz);
        odis = acc_s;
        omask = netmask_trace;
    }

    if (h == 0) {
        out[3*n + 0] = ox;
        out[3*n + 1] = oy;
        out[3*n + 2] = oz;
    } else {
        out[3*n_total + n] = omask ? 1.0f : 0.0f;
        out[4*n_total + n] = odis;
    }
}

extern "C" void kernel_launch(void* const* d_in, const int* in_sizes, int n_in,
                              void* d_out, int out_size, void* d_ws, size_t ws_size,
                              hipStream_t stream) {
    const float* cam_loc    = (const float*)d_in[0];
    const float* ray_dirs   = (const float*)d_in[1];
    // d_in[2] = object_mask (unused in eval-mode forward)
    const float* sdf_center = (const float*)d_in[3];
    const float* sdf_radius = (const float*)d_in[4];
    float* out = (float*)d_out;

    int n_total = in_sizes[1] / 3;   // B*P rays
    int threads = 2 * n_total;       // 2 lanes per ray
    int block = 256;
    int grid = (threads + block - 1) / block;
    ray_kernel<<<grid, block, 0, stream>>>(cam_loc, ray_dirs, sdf_center,
                                           sdf_radius, out, n_total);
}

// Round 7
// 13.008 us; speedup vs baseline: 1.4181x; 1.4181x over previous
//
#include <hip/hip_runtime.h>

// RayTracing: B=4, P=32768 rays, analytic sphere SDF.
// R3 skeleton, 4 lanes/ray: lanes q={0,2} trace the start end, q={1,3} the
// far end (duplicated across the pair halves -> same wall latency, but the
// 100-step march splits 4-way = 25 iters/lane, and the grid doubles to
// 8 waves/SIMD for latency hiding). All intra-quad exchanges use DPP
// quad_perm (pure VALU, ~4cyc) instead of ds_swizzle (~30cyc in the serial
// trace chain). Secant replaced by the analytic f32 root of u(z)=rad^2.
// March predicate bit-identical to the passing R3 kernel.

#define SDF_THR   5e-05f
#define NSTEPS    100
#define NTRACE    10

__device__ __forceinline__ float fsqrt(float x) {
    float r; asm("v_sqrt_f32 %0, %1" : "=v"(r) : "v"(x)); return r;
}
__device__ __forceinline__ float frcp(float x) {
    float r; asm("v_rcp_f32 %0, %1" : "=v"(r) : "v"(x)); return r;
}
// quad_perm [1,0,3,2]: swap neighbor lanes within each aligned quad
__device__ __forceinline__ float dpp_xor1(float x) {
    return __int_as_float(__builtin_amdgcn_update_dpp(
        0, __float_as_int(x), 0xB1, 0xF, 0xF, true));
}
__device__ __forceinline__ int dpp_xor1_i(int x) {
    return __builtin_amdgcn_update_dpp(0, x, 0xB1, 0xF, 0xF, true);
}
// quad_perm [2,3,0,1]: swap pair halves within each aligned quad
__device__ __forceinline__ float dpp_xor2(float x) {
    return __int_as_float(__builtin_amdgcn_update_dpp(
        0, __float_as_int(x), 0x4E, 0xF, 0xF, true));
}

__global__ __launch_bounds__(256) void ray_kernel(
    const float* __restrict__ cam_loc,     // [B,3]
    const float* __restrict__ ray_dirs,    // [B,P,3]
    const float* __restrict__ sdf_center,  // [3]
    const float* __restrict__ sdf_radius,  // [1]
    float* __restrict__ out,               // [3N pts | N mask | N dist]
    int n_total)
{
    const int t = blockIdx.x * blockDim.x + threadIdx.x;
    const int n = t >> 2;                  // ray index (4 lanes per ray)
    const int q = t & 3;                   // lane within quad
    const int h = q & 1;                   // 0 = start end, 1 = far end
    if (n >= n_total) return;
    const int b = n >> 15;                 // n / P, P = 32768

    const float dx = ray_dirs[3*n+0], dy = ray_dirs[3*n+1], dz = ray_dirs[3*n+2];
    const float cx = cam_loc[3*b+0], cy = cam_loc[3*b+1], cz = cam_loc[3*b+2];
    const float scx = sdf_center[0], scy = sdf_center[1], scz = sdf_center[2];
    const float rad = sdf_radius[0];

    // v_sqrt-consistent thresholds, hoisted so they overlap trace bubbles:
    //   fsqrt(u) < rad  <=> u <= u_neg_max ; fsqrt(u) <= rad <=> u <= u_le_max
    const float r2 = rad * rad;
    unsigned rb = __float_as_uint(r2);
    float u_neg_max = __uint_as_float(rb - 7u);
    float u_le_max  = u_neg_max;
    #pragma unroll
    for (int k = -6; k <= 6; ++k) {
        float u = __uint_as_float(rb + (unsigned)k);
        float v = fsqrt(u);
        if (v <  rad) u_neg_max = u;   // ascending: last wins = max
        if (v <= rad) u_le_max  = u;
    }

    // quadratic coeffs of squared distance along ray (+1e-12 folded in)
    const float ex = cx - scx, ey = cy - scy, ez = cz - scz;
    const float dd  = dx*dx + dy*dy + dz*dz;
    const float de2 = 2.0f * (dx*ex + dy*ey + dz*ez);
    const float ee1 = (ex*ex + ey*ey + ez*ez) + 1e-12f;

    // ---- bounding-sphere intersection (R=1) ----
    float rcd  = dx*cx + dy*cy + dz*cz;
    float cam2 = cx*cx + cy*cy + cz*cz;
    float under = rcd*rcd - (cam2 - 1.0f);
    bool mask_int = under > 0.0f;
    float sq = fsqrt(mask_int ? under : 0.0f);
    float si0 = fmaxf(mask_int ? (-sq - rcd) : 0.0f, 0.0f);
    float si1 = fmaxf(mask_int ? ( sq - rcd) : 0.0f, 0.0f);

    // ---- sphere tracing: this lane owns one end (duplicated across halves) ----
    float my_acc = h ? si1 : si0;
    const float sgn = h ? -1.0f : 1.0f;     // s end adds, e end subtracts
    bool my_unfin = mask_int;
    float next;
    {
        float u0 = fmaf(my_acc, fmaf(my_acc, dd, de2), ee1);
        next = my_unfin ? (fsqrt(u0) - rad) : 0.0f;
    }

    float acc_s = my_acc, acc_e = my_acc;
    #pragma unroll
    for (int it = 0; it < NTRACE; ++it) {
        float curr = my_unfin ? next : 0.0f;
        curr = (curr <= SDF_THR) ? 0.0f : curr;
        my_unfin = my_unfin && (curr > SDF_THR);
        my_acc = fmaf(sgn, curr, my_acc);
        float u = fmaf(my_acc, fmaf(my_acc, dd, de2), ee1);
        next = my_unfin ? (fsqrt(u) - rad) : 0.0f;
        // line-search back-off: exact SDF -> essentially never taken
        if (next < 0.0f) {
            my_acc = fmaf(-sgn, 0.5f * curr, my_acc);
            float u2 = fmaf(my_acc, fmaf(my_acc, dd, de2), ee1);
            next = fsqrt(u2) - rad;
        }
        float pacc = dpp_xor1(my_acc);      // partner end's acc (VALU, no LDS)
        acc_s = h ? pacc : my_acc;
        acc_e = h ? my_acc : pacc;
        bool ok = acc_s < acc_e;
        my_unfin = my_unfin && ok;
    }
    // final mask refresh (only the s-lane's value matters for the ray)
    bool sampler_s = my_unfin;
    {
        float curr = my_unfin ? next : 0.0f;
        curr = (curr <= SDF_THR) ? 0.0f : curr;
        sampler_s = my_unfin && (curr > SDF_THR);
    }
    const bool netmask_trace = acc_s < acc_e;

    // ray-level sampler flag on all 4 lanes
    int fs = h ? 0 : (int)sampler_s;
    int other = dpp_xor1_i(fs);
    const bool sampler = h ? (other != 0) : sampler_s;

    // ---- dense march (25 steps/lane) + analytic secant ----
    bool net_surface = false;
    float z_pred = 0.0f, zh_out = 0.0f;
    float pix = 0.0f, piy = 0.0f, piz = 0.0f;

    if (__ballot(sampler) != 0ULL) {
        const float smin = sampler ? acc_s : 0.0f;
        const float smax = sampler ? acc_e : 0.0f;
        const float sz = (smax - smin) * (1.0f / 99.0f);   // z_i = fma(i,sz,smin)

        // strided first-(sdf<=0) scan: lane q covers i = q, q+4, ...
        float kmf = 1e30f;
        float i_f = (float)q;
        #pragma unroll
        for (int s = 0; s < NSTEPS / 4; ++s) {
            float z = fmaf(i_f, sz, smin);
            float u = fmaf(z, fmaf(z, dd, de2), ee1);
            kmf = fminf(kmf, (u <= u_le_max) ? i_f : 1e30f);
            i_f += 4.0f;
        }
        kmf = fminf(kmf, dpp_xor1(kmf));    // combine across the quad
        kmf = fminf(kmf, dpp_xor2(kmf));

        int ind;
        if (kmf < 1e29f) {
            int km = (int)kmf;
            float zk = fmaf(kmf, sz, smin);
            float uk = fmaf(zk, fmaf(zk, dd, de2), ee1);
            if (uk <= u_neg_max) {
                ind = km; net_surface = true;     // first crossing is negative
            } else {
                // exact-tie (sdf==0) at km: reference prefers first NEGATIVE
                ind = km; net_surface = false;
                for (int i = km + 1; i < NSTEPS; ++i) {
                    float z = fmaf((float)i, sz, smin);
                    float u = fmaf(z, fmaf(z, dd, de2), ee1);
                    if (u <= u_neg_max) { ind = i; net_surface = true; break; }
                }
            }
        } else {
            ind = NSTEPS - 1; net_surface = false;
        }

        zh_out = fmaf((float)ind, sz, smin);      // reference outputs z[ind]
        pix = fmaf(zh_out, dx, cx);
        piy = fmaf(zh_out, dy, cy);
        piz = fmaf(zh_out, dz, cz);

        // analytic replacement of the 8-iter secant: entry root of u(z)=rad^2.
        // Only consumed when net_surface (true bracket: sdf>5e-5 at smin, so
        // ind>=1, sdf_low>0, sdf_high<0 -> unique entry root in the bracket).
        float Bh = 0.5f * de2;
        float disc2 = fmaf(-dd, ee1 - r2, Bh * Bh);
        z_pred = (-Bh - fsqrt(fmaxf(disc2, 0.0f))) * frcp(dd);
    }

    // ---- final selection ----
    float ox, oy, oz, odis;
    bool omask;
    if (sampler) {
        if (net_surface) {
            ox = fmaf(z_pred, dx, cx);
            oy = fmaf(z_pred, dy, cy);
            oz = fmaf(z_pred, dz, cz);
            odis = z_pred;
        } else {
            ox = pix; oy = piy; oz = piz;
            odis = zh_out;
        }
        omask = net_surface;
    } else {
        ox = fmaf(acc_s, dx, cx);
        oy = fmaf(acc_s, dy, cy);
        oz = fmaf(acc_s, dz, cz);
        odis = acc_s;
        omask = netmask_trace;
    }

    if (q == 0) {
        out[3*n + 0] = ox;
        out[3*n + 1] = oy;
        out[3*n + 2] = oz;
    } else if (q == 1) {
        out[3*n_total + n] = omask ? 1.0f : 0.0f;
    } else if (q == 2) {
        out[4*n_total + n] = odis;
    }
}

extern "C" void kernel_launch(void* const* d_in, const int* in_sizes, int n_in,
                              void* d_out, int out_size, void* d_ws, size_t ws_size,
                              hipStream_t stream) {
    const float* cam_loc    = (const float*)d_in[0];
    const float* ray_dirs   = (const float*)d_in[1];
    // d_in[2] = object_mask (unused in eval-mode forward)
    const float* sdf_center = (const float*)d_in[3];
    const float* sdf_radius = (const float*)d_in[4];
    float* out = (float*)d_out;

    int n_total = in_sizes[1] / 3;   // B*P rays
    int threads = 4 * n_total;       // 4 lanes per ray
    int block = 256;
    int grid = (threads + block - 1) / block;
    ray_kernel<<<grid, block, 0, stream>>>(cam_loc, ray_dirs, sdf_center,
                                           sdf_radius, out, n_total);
}

// Round 8
// 11.129 us; speedup vs baseline: 1.6575x; 1.1689x over previous
//
#include <hip/hip_runtime.h>

// RayTracing: B=4, P=32768 rays, analytic sphere SDF.
// Best-measured launch geometry (R3: 2 lanes/ray, 4096 waves, 1024 wg)
// + R7's verified tail cheapeners: DPP quad_perm pair exchange (no LDS
// round-trip in the serial trace chain) and analytic secant root.
// All SDF evals use the per-ray quadratic u(z) = dd z^2 + de2 z + (ee+1e-12),
// with sqrt-free sign classification against v_sqrt-consistent thresholds.

#define SDF_THR   5e-05f
#define NSTEPS    100
#define NTRACE    10

__device__ __forceinline__ float fsqrt(float x) {
    float r; asm("v_sqrt_f32 %0, %1" : "=v"(r) : "v"(x)); return r;
}
__device__ __forceinline__ float frcp(float x) {
    float r; asm("v_rcp_f32 %0, %1" : "=v"(r) : "v"(x)); return r;
}
// quad_perm [1,0,3,2]: swap neighbor lanes (pair partner), pure VALU
__device__ __forceinline__ float dpp_xor1(float x) {
    return __int_as_float(__builtin_amdgcn_update_dpp(
        0, __float_as_int(x), 0xB1, 0xF, 0xF, true));
}
__device__ __forceinline__ int dpp_xor1_i(int x) {
    return __builtin_amdgcn_update_dpp(0, x, 0xB1, 0xF, 0xF, true);
}

__global__ __launch_bounds__(256) void ray_kernel(
    const float* __restrict__ cam_loc,     // [B,3]
    const float* __restrict__ ray_dirs,    // [B,P,3]
    const float* __restrict__ sdf_center,  // [3]
    const float* __restrict__ sdf_radius,  // [1]
    float* __restrict__ out,               // [3N pts | N mask | N dist]
    int n_total)
{
    const int t = blockIdx.x * blockDim.x + threadIdx.x;
    const int n = t >> 1;                  // ray index (2 lanes per ray)
    const int h = t & 1;                   // 0 = start end, 1 = far end
    if (n >= n_total) return;
    const int b = n >> 15;                 // n / P, P = 32768

    const float dx = ray_dirs[3*n+0], dy = ray_dirs[3*n+1], dz = ray_dirs[3*n+2];
    const float cx = cam_loc[3*b+0], cy = cam_loc[3*b+1], cz = cam_loc[3*b+2];
    const float scx = sdf_center[0], scy = sdf_center[1], scz = sdf_center[2];
    const float rad = sdf_radius[0];

    // v_sqrt-consistent thresholds, hoisted to overlap trace bubbles:
    //   fsqrt(u) < rad  <=> u <= u_neg_max ; fsqrt(u) <= rad <=> u <= u_le_max
    const float r2 = rad * rad;
    unsigned rb = __float_as_uint(r2);
    float u_neg_max = __uint_as_float(rb - 7u);
    float u_le_max  = u_neg_max;
    #pragma unroll
    for (int k = -6; k <= 6; ++k) {
        float u = __uint_as_float(rb + (unsigned)k);
        float v = fsqrt(u);
        if (v <  rad) u_neg_max = u;   // ascending: last wins = max
        if (v <= rad) u_le_max  = u;
    }

    // quadratic coeffs of squared distance along ray (+1e-12 folded in)
    const float ex = cx - scx, ey = cy - scy, ez = cz - scz;
    const float dd  = dx*dx + dy*dy + dz*dz;
    const float de2 = 2.0f * (dx*ex + dy*ey + dz*ez);
    const float ee1 = (ex*ex + ey*ey + ez*ez) + 1e-12f;

    // ---- bounding-sphere intersection (R=1) ----
    float rcd  = dx*cx + dy*cy + dz*cz;
    float cam2 = cx*cx + cy*cy + cz*cz;
    float under = rcd*rcd - (cam2 - 1.0f);
    bool mask_int = under > 0.0f;
    float sq = fsqrt(mask_int ? under : 0.0f);
    float si0 = fmaxf(mask_int ? (-sq - rcd) : 0.0f, 0.0f);
    float si1 = fmaxf(mask_int ? ( sq - rcd) : 0.0f, 0.0f);

    // ---- sphere tracing: this lane owns one end ----
    float my_acc = h ? si1 : si0;
    const float sgn = h ? -1.0f : 1.0f;     // s end adds, e end subtracts
    bool my_unfin = mask_int;
    float next;
    {
        float u0 = fmaf(my_acc, fmaf(my_acc, dd, de2), ee1);
        next = my_unfin ? (fsqrt(u0) - rad) : 0.0f;
    }

    float acc_s = my_acc, acc_e = my_acc;
    #pragma unroll
    for (int it = 0; it < NTRACE; ++it) {
        float curr = my_unfin ? next : 0.0f;
        curr = (curr <= SDF_THR) ? 0.0f : curr;
        my_unfin = my_unfin && (curr > SDF_THR);
        my_acc = fmaf(sgn, curr, my_acc);
        float u = fmaf(my_acc, fmaf(my_acc, dd, de2), ee1);
        next = my_unfin ? (fsqrt(u) - rad) : 0.0f;
        // line-search back-off: exact SDF -> essentially never taken
        if (next < 0.0f) {
            my_acc = fmaf(-sgn, 0.5f * curr, my_acc);
            float u2 = fmaf(my_acc, fmaf(my_acc, dd, de2), ee1);
            next = fsqrt(u2) - rad;
        }
        float pacc = dpp_xor1(my_acc);      // partner end's acc (VALU, no LDS)
        acc_s = h ? pacc : my_acc;
        acc_e = h ? my_acc : pacc;
        bool ok = acc_s < acc_e;
        my_unfin = my_unfin && ok;
    }
    // final mask refresh (only the s-lane's value matters for the ray)
    bool sampler_s = my_unfin;
    {
        float curr = my_unfin ? next : 0.0f;
        curr = (curr <= SDF_THR) ? 0.0f : curr;
        sampler_s = my_unfin && (curr > SDF_THR);
    }
    const bool netmask_trace = acc_s < acc_e;

    // ray-level sampler flag on both lanes
    int fs = h ? 0 : (int)sampler_s;
    int other = dpp_xor1_i(fs);
    const bool sampler = h ? (other != 0) : sampler_s;

    // ---- dense march (50 steps/lane) + analytic secant ----
    bool net_surface = false;
    float z_pred = 0.0f, zh_out = 0.0f;
    float pix = 0.0f, piy = 0.0f, piz = 0.0f;

    if (__ballot(sampler) != 0ULL) {
        const float smin = sampler ? acc_s : 0.0f;
        const float smax = sampler ? acc_e : 0.0f;
        const float sz = (smax - smin) * (1.0f / 99.0f);   // z_i = fma(i,sz,smin)

        // strided first-(sdf<=0) scan: lane h covers i = h, h+2, ...
        float kmf = 1e30f;
        float i_f = (float)h;
        #pragma unroll
        for (int s = 0; s < NSTEPS / 2; ++s) {
            float z = fmaf(i_f, sz, smin);
            float u = fmaf(z, fmaf(z, dd, de2), ee1);
            kmf = fminf(kmf, (u <= u_le_max) ? i_f : 1e30f);
            i_f += 2.0f;
        }
        kmf = fminf(kmf, dpp_xor1(kmf));    // combine across the pair

        int ind;
        if (kmf < 1e29f) {
            int km = (int)kmf;
            float zk = fmaf(kmf, sz, smin);
            float uk = fmaf(zk, fmaf(zk, dd, de2), ee1);
            if (uk <= u_neg_max) {
                ind = km; net_surface = true;     // first crossing is negative
            } else {
                // exact-tie (sdf==0) at km: reference prefers first NEGATIVE
                ind = km; net_surface = false;
                for (int i = km + 1; i < NSTEPS; ++i) {
                    float z = fmaf((float)i, sz, smin);
                    float u = fmaf(z, fmaf(z, dd, de2), ee1);
                    if (u <= u_neg_max) { ind = i; net_surface = true; break; }
                }
            }
        } else {
            ind = NSTEPS - 1; net_surface = false;
        }

        zh_out = fmaf((float)ind, sz, smin);      // reference outputs z[ind]
        pix = fmaf(zh_out, dx, cx);
        piy = fmaf(zh_out, dy, cy);
        piz = fmaf(zh_out, dz, cz);

        // analytic replacement of the 8-iter secant: entry root of u(z)=rad^2.
        // Only consumed when net_surface (true bracket: sdf>5e-5 at smin, so
        // ind>=1, sdf_low>0, sdf_high<0 -> unique entry root in the bracket).
        float Bh = 0.5f * de2;
        float disc2 = fmaf(-dd, ee1 - r2, Bh * Bh);
        z_pred = (-Bh - fsqrt(fmaxf(disc2, 0.0f))) * frcp(dd);
    }

    // ---- final selection ----
    float ox, oy, oz, odis;
    bool omask;
    if (sampler) {
        if (net_surface) {
            ox = fmaf(z_pred, dx, cx);
            oy = fmaf(z_pred, dy, cy);
            oz = fmaf(z_pred, dz, cz);
            odis = z_pred;
        } else {
            ox = pix; oy = piy; oz = piz;
            odis = zh_out;
        }
        omask = net_surface;
    } else {
        ox = fmaf(acc_s, dx, cx);
        oy = fmaf(acc_s, dy, cy);
        oz = fmaf(acc_s, dz, cz);
        odis = acc_s;
        omask = netmask_trace;
    }

    if (h == 0) {
        out[3*n + 0] = ox;
        out[3*n + 1] = oy;
        out[3*n + 2] = oz;
    } else {
        out[3*n_total + n] = omask ? 1.0f : 0.0f;
        out[4*n_total + n] = odis;
    }
}

extern "C" void kernel_launch(void* const* d_in, const int* in_sizes, int n_in,
                              void* d_out, int out_size, void* d_ws, size_t ws_size,
                              hipStream_t stream) {
    const float* cam_loc    = (const float*)d_in[0];
    const float* ray_dirs   = (const float*)d_in[1];
    // d_in[2] = object_mask (unused in eval-mode forward)
    const float* sdf_center = (const float*)d_in[3];
    const float* sdf_radius = (const float*)d_in[4];
    float* out = (float*)d_out;

    int n_total = in_sizes[1] / 3;   // B*P rays
    int threads = 2 * n_total;       // 2 lanes per ray
    int block = 256;
    int grid = (threads + block - 1) / block;
    ray_kernel<<<grid, block, 0, stream>>>(cam_loc, ray_dirs, sdf_center,
                                           sdf_radius, out, n_total);
}